// Round 5
// baseline (720.356 us; speedup 1.0000x reference)
//
#include <hip/hip_runtime.h>
#include <hip/hip_bf16.h>
#include <stdint.h>

#define NN 8192
#define DD 512

typedef unsigned short u16;
typedef unsigned long long u64;
typedef __attribute__((ext_vector_type(8))) short short8;
typedef __attribute__((ext_vector_type(4))) float f32x4;

// async global->LDS, 16B per lane; LDS dest = wave-uniform base + lane*16
__device__ __forceinline__ void gld_lds16(const void* g, void* l) {
  __builtin_amdgcn_global_load_lds(
      (const __attribute__((address_space(1))) uint32_t*)(uintptr_t)g,
      (__attribute__((address_space(3))) uint32_t*)(uintptr_t)l,
      16, 0, 0);
}

__device__ __forceinline__ u16 f2bf(float f) {
  __hip_bfloat16 b = __float2bfloat16(f);
  return __builtin_bit_cast(u16, b);
}

__global__ void fill_kernel(float* __restrict__ p, int n, float v) {
  int i = blockIdx.x * 256 + threadIdx.x;
  int stride = gridDim.x * 256;
  for (; i < n; i += stride) p[i] = v;
}

__global__ void cvt4_kernel(const float4* __restrict__ src, ushort4* __restrict__ dst, int n4) {
  int i = blockIdx.x * 256 + threadIdx.x;
  int stride = gridDim.x * 256;
  for (; i < n4; i += stride) {
    float4 v = src[i];
    ushort4 o;
    o.x = f2bf(v.x); o.y = f2bf(v.y); o.z = f2bf(v.z); o.w = f2bf(v.w);
    dst[i] = o;
  }
}

// adj (int32 0/1) -> bitmask (u64 word w of row: bit b = col 64w+b); also zeroes den
__global__ void pack_adj_kernel(const int* __restrict__ adj, u16* __restrict__ mask,
                                float* __restrict__ den) {
  const int row = blockIdx.x;
  const int t = threadIdx.x;
  if (t == 0) den[row] = 0.0f;
  const uint4* arow = (const uint4*)(adj + (size_t)row * NN);
  #pragma unroll
  for (int iter = 0; iter < 2; iter++) {
    const int c16 = iter * 256 + t;
    unsigned int bits = 0;
    #pragma unroll
    for (int g = 0; g < 4; g++) {
      uint4 v = arow[c16 * 4 + g];
      bits |= (v.x ? 1u : 0u) << (g * 4 + 0);
      bits |= (v.y ? 1u : 0u) << (g * 4 + 1);
      bits |= (v.z ? 1u : 0u) << (g * 4 + 2);
      bits |= (v.w ? 1u : 0u) << (g * 4 + 3);
    }
    mask[(size_t)row * (NN / 16) + c16] = (u16)bits;
  }
}

__global__ void rownorm_kernel(const float* __restrict__ Wh, float* __restrict__ invn) {
  int row = blockIdx.x;
  int l = threadIdx.x;  // 64
  const float4* p = (const float4*)(Wh + (size_t)row * DD);
  float4 a = p[l], b = p[l + 64];
  float s = a.x*a.x + a.y*a.y + a.z*a.z + a.w*a.w
          + b.x*b.x + b.y*b.y + b.z*b.z + b.w*b.w;
  #pragma unroll
  for (int off = 32; off; off >>= 1) s += __shfl_down(s, off);
  if (l == 0) invn[row] = 1.0f / sqrtf(s);
}

__global__ void u_wht_kernel(const float* __restrict__ Wh, const float* __restrict__ invn,
                             u16* __restrict__ U, u16* __restrict__ WhT) {
  __shared__ float tile[64][65];
  int i0 = blockIdx.x * 64, d0 = blockIdx.y * 64;
  int c = threadIdx.x & 63, rb = threadIdx.x >> 6;
  #pragma unroll
  for (int r = rb; r < 64; r += 4) {
    float v = Wh[(size_t)(i0 + r) * DD + d0 + c];
    tile[r][c] = v;
    U[(size_t)(i0 + r) * DD + d0 + c] = f2bf(v * invn[i0 + r]);
  }
  __syncthreads();
  #pragma unroll
  for (int r = rb; r < 64; r += 4) {
    WhT[(size_t)(d0 + r) * NN + i0 + c] = f2bf(tile[c][r]);
  }
}

// Wh-GEMM: C = A * B^T fp32, 128x128 tile, 256 thr.
__global__ void __launch_bounds__(256) gemm_wh(
    const u16* __restrict__ A, const u16* __restrict__ B,
    int Nn, int K, float* __restrict__ Cf)
{
  __shared__ __align__(16) u16 As[128 * 32];
  __shared__ __align__(16) u16 Bs[128 * 32];

  const int tid = threadIdx.x;
  const int w = tid >> 6;
  const int lane = tid & 63;
  const int lm = lane & 15;
  const int q = lane >> 4;
  const int row0 = blockIdx.y * 128;
  const int col0 = blockIdx.x * 128;
  const int RM = (w >> 1) * 64;
  const int RN = (w & 1) * 64;
  const int sr = tid >> 2;
  const int sk = (tid & 3) * 8;

  f32x4 acc[4][4];
  #pragma unroll
  for (int a_ = 0; a_ < 4; a_++)
    #pragma unroll
    for (int b_ = 0; b_ < 4; b_++)
      acc[a_][b_] = (f32x4){0.f, 0.f, 0.f, 0.f};

  const size_t Abase = (size_t)row0 * K;
  const size_t Bbase = (size_t)col0 * K;

  for (int k0 = 0; k0 < K; k0 += 32) {
    __syncthreads();
    gld_lds16(A + Abase + (size_t)sr * K + k0 + sk,        (char*)As + w * 1024);
    gld_lds16(A + Abase + (size_t)(sr + 64) * K + k0 + sk, (char*)As + 4096 + w * 1024);
    gld_lds16(B + Bbase + (size_t)sr * K + k0 + sk,        (char*)Bs + w * 1024);
    gld_lds16(B + Bbase + (size_t)(sr + 64) * K + k0 + sk, (char*)Bs + 4096 + w * 1024);
    __syncthreads();

    short8 af[4], bfr[4];
    #pragma unroll
    for (int mt = 0; mt < 4; mt++)
      af[mt] = *(const short8*)&As[(RM + mt * 16 + lm) * 32 + q * 8];
    #pragma unroll
    for (int nt = 0; nt < 4; nt++)
      bfr[nt] = *(const short8*)&Bs[(RN + nt * 16 + lm) * 32 + q * 8];

    #pragma unroll
    for (int mt = 0; mt < 4; mt++)
      #pragma unroll
      for (int nt = 0; nt < 4; nt++)
        acc[mt][nt] = __builtin_amdgcn_mfma_f32_16x16x32_bf16(af[mt], bfr[nt], acc[mt][nt], 0, 0, 0);
  }

  #pragma unroll
  for (int mt = 0; mt < 4; mt++) {
    const int ib = row0 + RM + mt * 16 + q * 4;
    #pragma unroll
    for (int rr = 0; rr < 4; rr++) {
      const int i = ib + rr;
      #pragma unroll
      for (int nt = 0; nt < 4; nt++) {
        const int jc = col0 + RN + nt * 16 + lm;
        Cf[(size_t)i * Nn + jc] = acc[mt][nt][rr];
      }
    }
  }
}

// Symmetric sim-GEMM v2: 128-row x 256-col tiles covering the lower triangle.
// Strip bi (128 rows) has floor(bi/2)+1 tiles of 256 cols -> 1056 blocks.
// Per-element predicates: write normal P[i][jc] iff jc<=i (diag OR'd in),
// mirror P[jc][i] iff jc<i. Overhang halves (jc>i) are skipped automatically.
// 256 thr = 4 waves, each wave a 64x128 quadrant (acc 4x8).
__global__ void __launch_bounds__(256) gemm_sim(
    const u16* __restrict__ U, const u64* __restrict__ maskw,
    u16* __restrict__ Pb, float* __restrict__ den)
{
  __shared__ __align__(16) u16 As[128 * 32];   // 8 KB
  __shared__ __align__(16) u16 Bs[256 * 32];   // 16 KB

  // decode linear block -> (bi strip, bj2 256-col tile)
  int b = blockIdx.x;
  int bi = 0, cum = 0;
  while (cum + ((bi >> 1) + 1) <= b) { cum += (bi >> 1) + 1; bi++; }
  const int bj2 = b - cum;

  const int tid = threadIdx.x;
  const int w = tid >> 6;
  const int lane = tid & 63;
  const int lm = lane & 15;
  const int q = lane >> 4;
  const int row0 = bi * 128;
  const int col0 = bj2 * 256;
  const int RM = (w >> 1) * 64;     // 0/64
  const int RN = (w & 1) * 128;     // 0/128

  f32x4 acc[4][8];
  #pragma unroll
  for (int a_ = 0; a_ < 4; a_++)
    #pragma unroll
    for (int b_ = 0; b_ < 8; b_++)
      acc[a_][b_] = (f32x4){0.f, 0.f, 0.f, 0.f};

  const size_t Abase = (size_t)row0 * DD;
  const size_t Bbase = (size_t)col0 * DD;
  const int sr4 = tid >> 2;         // 0..63 (row within 64-row group)
  const int sk4 = (tid & 3) * 8;    // k offset

  for (int k0 = 0; k0 < DD; k0 += 32) {
    __syncthreads();
    // A: 128x32 = 2 chunks of 64 rows
    #pragma unroll
    for (int c = 0; c < 2; c++)
      gld_lds16(U + Abase + (size_t)(c * 64 + sr4) * DD + k0 + sk4,
                (char*)As + c * 4096 + w * 1024);
    // B: 256x32 = 4 chunks of 64 rows
    #pragma unroll
    for (int c = 0; c < 4; c++)
      gld_lds16(U + Bbase + (size_t)(c * 64 + sr4) * DD + k0 + sk4,
                (char*)Bs + c * 4096 + w * 1024);
    __syncthreads();

    short8 af[4], bfr[8];
    #pragma unroll
    for (int mt = 0; mt < 4; mt++)
      af[mt] = *(const short8*)&As[(RM + mt * 16 + lm) * 32 + q * 8];
    #pragma unroll
    for (int nt = 0; nt < 8; nt++)
      bfr[nt] = *(const short8*)&Bs[(RN + nt * 16 + lm) * 32 + q * 8];

    #pragma unroll
    for (int mt = 0; mt < 4; mt++)
      #pragma unroll
      for (int nt = 0; nt < 8; nt++)
        acc[mt][nt] = __builtin_amdgcn_mfma_f32_16x16x32_bf16(af[mt], bfr[nt], acc[mt][nt], 0, 0, 0);
  }

  // C/D layout: col = lm, row = q*4 + rr
  const int wA = (col0 + RN) >> 6;           // normal mask word idx (first of 2)
  const int wM = (row0 + RM) >> 6;           // mirror mask word idx

  // mirror mask words, uniform over mt/rr
  u64 wrd2[8];
  #pragma unroll
  for (int nt = 0; nt < 8; nt++) {
    const int jc = col0 + RN + nt * 16 + lm;
    wrd2[nt] = maskw[(size_t)jc * (NN / 64) + wM];
  }

  float msum[8] = {0.f, 0.f, 0.f, 0.f, 0.f, 0.f, 0.f, 0.f};

  #pragma unroll
  for (int mt = 0; mt < 4; mt++) {
    const int ib = row0 + RM + mt * 16 + q * 4;
    float pm[8][4];
    #pragma unroll
    for (int rr = 0; rr < 4; rr++) {
      const int i = ib + rr;
      const u64 nw0 = maskw[(size_t)i * (NN / 64) + wA];
      const u64 nw1 = maskw[(size_t)i * (NN / 64) + wA + 1];
      const int bit2 = mt * 16 + q * 4 + rr;   // == i & 63 within this wave's RM
      float psum = 0.f;
      #pragma unroll
      for (int nt = 0; nt < 8; nt++) {
        const int jc = col0 + RN + nt * 16 + lm;
        const float ev = __expf(acc[mt][nt][rr]);
        const u64 nw = (nt < 4) ? nw0 : nw1;
        const bool on = ((nw >> ((nt * 16 + lm) & 63)) & 1ull) || (i == jc);
        // normal side: lower triangle incl diagonal
        if (jc <= i) {
          const float p = on ? ev : 0.0f;
          psum += p;
          Pb[(size_t)i * NN + jc] = f2bf(p);
        }
        // mirror side: strict upper triangle
        const bool on2 = (wrd2[nt] >> bit2) & 1ull;
        const float pmv = (jc < i && on2) ? ev : 0.0f;
        pm[nt][rr] = pmv;
        msum[nt] += pmv;
      }
      #pragma unroll
      for (int off = 8; off; off >>= 1) psum += __shfl_down(psum, off, 16);
      if (lm == 0) atomicAdd(&den[i], psum);
    }
    // mirror stores: contiguous over rr at Pb[jc*NN + ib..ib+3]
    #pragma unroll
    for (int nt = 0; nt < 8; nt++) {
      const int jc = col0 + RN + nt * 16 + lm;
      if (jc < ib) {
        ushort4 m4;
        m4.x = f2bf(pm[nt][0]); m4.y = f2bf(pm[nt][1]);
        m4.z = f2bf(pm[nt][2]); m4.w = f2bf(pm[nt][3]);
        *(ushort4*)&Pb[(size_t)jc * NN + ib] = m4;
      } else if (jc < ib + 4) {
        for (int rr = jc - ib + 1; rr < 4; rr++)
          Pb[(size_t)jc * NN + ib + rr] = f2bf(pm[nt][rr]);
      }
    }
  }

  // mirror den contributions: reduce over the 4 q-groups holding the same jc
  #pragma unroll
  for (int nt = 0; nt < 8; nt++) {
    float s = msum[nt];
    s += __shfl_xor(s, 16);
    s += __shfl_xor(s, 32);
    if (q == 0) atomicAdd(&den[col0 + RN + nt * 16 + lm], s);
  }
}

// out-GEMM: tile 128 rows x FULL N=512, 512 threads (8 waves, each 64x128).
// Split-K=8 via blockIdx.y; partial z stored bf16 at part + z*NN*DD.
__global__ void __launch_bounds__(512, 2) gemm_out(
    const u16* __restrict__ A,    // P [NN x NN]
    const u16* __restrict__ B,    // WhT [DD x NN]
    u16* __restrict__ part)
{
  __shared__ __align__(16) u16 As[128 * 32];   // 8 KB
  __shared__ __align__(16) u16 Bs[512 * 32];   // 32 KB

  const int tid = threadIdx.x;
  const int w = tid >> 6;        // 0..7
  const int lane = tid & 63;
  const int lm = lane & 15;
  const int q = lane >> 4;
  const int row0 = blockIdx.x * 128;
  const int z = blockIdx.y;      // 0..7
  const int RM = (w >> 2) * 64;  // 0/64
  const int RN = (w & 3) * 128;  // 0..384
  const int sr = tid >> 2;       // 0..127
  const int sk = (tid & 3) * 8;

  f32x4 acc[4][8];
  #pragma unroll
  for (int a_ = 0; a_ < 4; a_++)
    #pragma unroll
    for (int b_ = 0; b_ < 8; b_++)
      acc[a_][b_] = (f32x4){0.f, 0.f, 0.f, 0.f};

  const size_t Abase = (size_t)row0 * NN;
  const int kBegin = z * (NN / 8), kEnd = (z + 1) * (NN / 8);

  for (int k0 = kBegin; k0 < kEnd; k0 += 32) {
    __syncthreads();
    gld_lds16(A + Abase + (size_t)sr * NN + k0 + sk, (char*)As + w * 1024);
    #pragma unroll
    for (int c = 0; c < 4; c++)
      gld_lds16(B + (size_t)(c * 128 + sr) * NN + k0 + sk, (char*)Bs + c * 8192 + w * 1024);
    __syncthreads();

    short8 af[4], bfr[8];
    #pragma unroll
    for (int mt = 0; mt < 4; mt++)
      af[mt] = *(const short8*)&As[(RM + mt * 16 + lm) * 32 + q * 8];
    #pragma unroll
    for (int nt = 0; nt < 8; nt++)
      bfr[nt] = *(const short8*)&Bs[(RN + nt * 16 + lm) * 32 + q * 8];

    #pragma unroll
    for (int mt = 0; mt < 4; mt++)
      #pragma unroll
      for (int nt = 0; nt < 8; nt++)
        acc[mt][nt] = __builtin_amdgcn_mfma_f32_16x16x32_bf16(af[mt], bfr[nt], acc[mt][nt], 0, 0, 0);
  }

  u16* const pz = part + (size_t)z * NN * DD;
  #pragma unroll
  for (int mt = 0; mt < 4; mt++) {
    const int ib = row0 + RM + mt * 16 + q * 4;
    #pragma unroll
    for (int rr = 0; rr < 4; rr++) {
      const int i = ib + rr;
      #pragma unroll
      for (int nt = 0; nt < 8; nt++) {
        const int dc = RN + nt * 16 + lm;
        pz[(size_t)i * DD + dc] = f2bf(acc[mt][nt][rr]);
      }
    }
  }
}

// out = (sum of 8 bf16 partials) / den[row]; each thread handles 8 cols
__global__ void reduce8_kernel(const u16* __restrict__ part,
                               const float* __restrict__ den, float4* __restrict__ out) {
  const int idx = blockIdx.x * 256 + threadIdx.x;   // NN*DD/8 units of 8 cols
  const int row = idx >> 6;                          // 64 units per row
  const float dinv = 1.0f / den[row];
  float s[8] = {0, 0, 0, 0, 0, 0, 0, 0};
  #pragma unroll
  for (int zp = 0; zp < 8; zp++) {
    const uint4 u = ((const uint4*)(part + (size_t)zp * NN * DD))[idx];
    s[0] += __uint_as_float(u.x << 16); s[1] += __uint_as_float(u.x & 0xffff0000u);
    s[2] += __uint_as_float(u.y << 16); s[3] += __uint_as_float(u.y & 0xffff0000u);
    s[4] += __uint_as_float(u.z << 16); s[5] += __uint_as_float(u.z & 0xffff0000u);
    s[6] += __uint_as_float(u.w << 16); s[7] += __uint_as_float(u.w & 0xffff0000u);
  }
  float4 o0 = {s[0] * dinv, s[1] * dinv, s[2] * dinv, s[3] * dinv};
  float4 o1 = {s[4] * dinv, s[5] * dinv, s[6] * dinv, s[7] * dinv};
  out[idx * 2] = o0;
  out[idx * 2 + 1] = o1;
}

extern "C" void kernel_launch(void* const* d_in, const int* in_sizes, int n_in,
                              void* d_out, int out_size, void* d_ws, size_t ws_size,
                              hipStream_t stream) {
  const float* h = (const float*)d_in[0];
  const int* adj = (const int*)d_in[1];
  const float* W = (const float*)d_in[2];
  float* out = (float*)d_out;

  const size_t SZ_P    = (size_t)NN * NN * 2;          // 134.2 MB
  const size_t SZ_MASK = (size_t)NN * NN / 8;          // 8.4 MB
  const size_t SZ_WHT  = (size_t)DD * NN * 2;          // 8.4 MB
  const size_t SZ_HB   = (size_t)NN * DD * 2;          // 8.4 MB
  const size_t SZ_WB   = (size_t)DD * DD * 2;          // 0.5 MB
  const size_t SZ_U    = (size_t)NN * DD * 2;          // 8.4 MB
  const size_t SZ_WH   = (size_t)NN * DD * 4;          // 16.8 MB
  const size_t SZ_PART = (size_t)8 * NN * DD * 2;      // 67.1 MB
  const size_t NEEDED  = SZ_P + SZ_MASK + SZ_WHT + SZ_HB + SZ_WB + SZ_U + SZ_WH
                       + SZ_PART + 2 * (size_t)NN * 4;

  if (ws_size < NEEDED) {
    fill_kernel<<<256, 256, 0, stream>>>(out, out_size, 12345.0f);
    return;
  }

  char* ws = (char*)d_ws;
  size_t off = 0;
  u16*   P    = (u16*)(ws + off); off += SZ_P;
  u16*   mask = (u16*)(ws + off); off += SZ_MASK;
  u16*   WhT  = (u16*)(ws + off); off += SZ_WHT;
  u16*   hb   = (u16*)(ws + off); off += SZ_HB;
  u16*   Wb   = (u16*)(ws + off); off += SZ_WB;
  u16*   U    = (u16*)(ws + off); off += SZ_U;
  float* Wh   = (float*)(ws + off); off += SZ_WH;
  u16*   part = (u16*)(ws + off); off += SZ_PART;
  float* invn = (float*)(ws + off);
  float* den  = invn + NN;

  pack_adj_kernel<<<NN, 256, 0, stream>>>(adj, mask, den);
  cvt4_kernel<<<1024, 256, 0, stream>>>((const float4*)h, (ushort4*)hb, NN * DD / 4);
  cvt4_kernel<<<256, 256, 0, stream>>>((const float4*)W, (ushort4*)Wb, DD * DD / 4);
  // Wh = h @ W^T
  gemm_wh<<<dim3(DD / 128, NN / 128), 256, 0, stream>>>(hb, Wb, DD, DD, Wh);
  rownorm_kernel<<<NN, 64, 0, stream>>>(Wh, invn);
  u_wht_kernel<<<dim3(NN / 64, DD / 64), 256, 0, stream>>>(Wh, invn, U, WhT);
  // P = mask ? exp(U U^T) : 0 (bf16), symmetric 128x256 tiles, fused den
  gemm_sim<<<1056, 256, 0, stream>>>(U, (const u64*)mask, P, den);
  // out partials: full-N tile, split-K=8 (P read exactly once)
  gemm_out<<<dim3(NN / 128, 8), 512, 0, stream>>>(P, WhT, part);
  // out = sum(partials) / den
  reduce8_kernel<<<NN * DD / 8 / 256, 256, 0, stream>>>(part, den, (float4*)out);
}

// Round 6
// 655.197 us; speedup vs baseline: 1.0994x; 1.0994x over previous
//
#include <hip/hip_runtime.h>
#include <hip/hip_bf16.h>
#include <stdint.h>

#define NN 8192
#define DD 512

typedef unsigned short u16;
typedef unsigned long long u64;
typedef __attribute__((ext_vector_type(8))) short short8;
typedef __attribute__((ext_vector_type(4))) float f32x4;

// async global->LDS, 16B per lane; LDS dest = wave-uniform base + lane*16
__device__ __forceinline__ void gld_lds16(const void* g, void* l) {
  __builtin_amdgcn_global_load_lds(
      (const __attribute__((address_space(1))) uint32_t*)(uintptr_t)g,
      (__attribute__((address_space(3))) uint32_t*)(uintptr_t)l,
      16, 0, 0);
}

__device__ __forceinline__ u16 f2bf(float f) {
  __hip_bfloat16 b = __float2bfloat16(f);
  return __builtin_bit_cast(u16, b);
}

__global__ void fill_kernel(float* __restrict__ p, int n, float v) {
  int i = blockIdx.x * 256 + threadIdx.x;
  int stride = gridDim.x * 256;
  for (; i < n; i += stride) p[i] = v;
}

__global__ void cvt4_kernel(const float4* __restrict__ src, ushort4* __restrict__ dst, int n4) {
  int i = blockIdx.x * 256 + threadIdx.x;
  int stride = gridDim.x * 256;
  for (; i < n4; i += stride) {
    float4 v = src[i];
    ushort4 o;
    o.x = f2bf(v.x); o.y = f2bf(v.y); o.z = f2bf(v.z); o.w = f2bf(v.w);
    dst[i] = o;
  }
}

// adj (int32 0/1) -> bitmask (u64 word w of row: bit b = col 64w+b); also zeroes den
__global__ void pack_adj_kernel(const int* __restrict__ adj, u16* __restrict__ mask,
                                float* __restrict__ den) {
  const int row = blockIdx.x;
  const int t = threadIdx.x;
  if (t == 0) den[row] = 0.0f;
  const uint4* arow = (const uint4*)(adj + (size_t)row * NN);
  #pragma unroll
  for (int iter = 0; iter < 2; iter++) {
    const int c16 = iter * 256 + t;
    unsigned int bits = 0;
    #pragma unroll
    for (int g = 0; g < 4; g++) {
      uint4 v = arow[c16 * 4 + g];
      bits |= (v.x ? 1u : 0u) << (g * 4 + 0);
      bits |= (v.y ? 1u : 0u) << (g * 4 + 1);
      bits |= (v.z ? 1u : 0u) << (g * 4 + 2);
      bits |= (v.w ? 1u : 0u) << (g * 4 + 3);
    }
    mask[(size_t)row * (NN / 16) + c16] = (u16)bits;
  }
}

__global__ void rownorm_kernel(const float* __restrict__ Wh, float* __restrict__ invn) {
  int row = blockIdx.x;
  int l = threadIdx.x;  // 64
  const float4* p = (const float4*)(Wh + (size_t)row * DD);
  float4 a = p[l], b = p[l + 64];
  float s = a.x*a.x + a.y*a.y + a.z*a.z + a.w*a.w
          + b.x*b.x + b.y*b.y + b.z*b.z + b.w*b.w;
  #pragma unroll
  for (int off = 32; off; off >>= 1) s += __shfl_down(s, off);
  if (l == 0) invn[row] = 1.0f / sqrtf(s);
}

__global__ void u_wht_kernel(const float* __restrict__ Wh, const float* __restrict__ invn,
                             u16* __restrict__ U, u16* __restrict__ WhT) {
  __shared__ float tile[64][65];
  int i0 = blockIdx.x * 64, d0 = blockIdx.y * 64;
  int c = threadIdx.x & 63, rb = threadIdx.x >> 6;
  #pragma unroll
  for (int r = rb; r < 64; r += 4) {
    float v = Wh[(size_t)(i0 + r) * DD + d0 + c];
    tile[r][c] = v;
    U[(size_t)(i0 + r) * DD + d0 + c] = f2bf(v * invn[i0 + r]);
  }
  __syncthreads();
  #pragma unroll
  for (int r = rb; r < 64; r += 4) {
    WhT[(size_t)(d0 + r) * NN + i0 + c] = f2bf(tile[c][r]);
  }
}

// Wh-GEMM: C = A * B^T fp32, 128x128 tile, 256 thr.
__global__ void __launch_bounds__(256) gemm_wh(
    const u16* __restrict__ A, const u16* __restrict__ B,
    int Nn, int K, float* __restrict__ Cf)
{
  __shared__ __align__(16) u16 As[128 * 32];
  __shared__ __align__(16) u16 Bs[128 * 32];

  const int tid = threadIdx.x;
  const int w = tid >> 6;
  const int lane = tid & 63;
  const int lm = lane & 15;
  const int q = lane >> 4;
  const int row0 = blockIdx.y * 128;
  const int col0 = blockIdx.x * 128;
  const int RM = (w >> 1) * 64;
  const int RN = (w & 1) * 64;
  const int sr = tid >> 2;
  const int sk = (tid & 3) * 8;

  f32x4 acc[4][4];
  #pragma unroll
  for (int a_ = 0; a_ < 4; a_++)
    #pragma unroll
    for (int b_ = 0; b_ < 4; b_++)
      acc[a_][b_] = (f32x4){0.f, 0.f, 0.f, 0.f};

  const size_t Abase = (size_t)row0 * K;
  const size_t Bbase = (size_t)col0 * K;

  for (int k0 = 0; k0 < K; k0 += 32) {
    __syncthreads();
    gld_lds16(A + Abase + (size_t)sr * K + k0 + sk,        (char*)As + w * 1024);
    gld_lds16(A + Abase + (size_t)(sr + 64) * K + k0 + sk, (char*)As + 4096 + w * 1024);
    gld_lds16(B + Bbase + (size_t)sr * K + k0 + sk,        (char*)Bs + w * 1024);
    gld_lds16(B + Bbase + (size_t)(sr + 64) * K + k0 + sk, (char*)Bs + 4096 + w * 1024);
    __syncthreads();

    short8 af[4], bfr[4];
    #pragma unroll
    for (int mt = 0; mt < 4; mt++)
      af[mt] = *(const short8*)&As[(RM + mt * 16 + lm) * 32 + q * 8];
    #pragma unroll
    for (int nt = 0; nt < 4; nt++)
      bfr[nt] = *(const short8*)&Bs[(RN + nt * 16 + lm) * 32 + q * 8];

    #pragma unroll
    for (int mt = 0; mt < 4; mt++)
      #pragma unroll
      for (int nt = 0; nt < 4; nt++)
        acc[mt][nt] = __builtin_amdgcn_mfma_f32_16x16x32_bf16(af[mt], bfr[nt], acc[mt][nt], 0, 0, 0);
  }

  #pragma unroll
  for (int mt = 0; mt < 4; mt++) {
    const int ib = row0 + RM + mt * 16 + q * 4;
    #pragma unroll
    for (int rr = 0; rr < 4; rr++) {
      const int i = ib + rr;
      #pragma unroll
      for (int nt = 0; nt < 4; nt++) {
        const int jc = col0 + RN + nt * 16 + lm;
        Cf[(size_t)i * Nn + jc] = acc[mt][nt][rr];
      }
    }
  }
}

// Symmetric sim-GEMM (R4 structure — stays under the 128-VGPR occupancy cliff):
// lower-tri 128x128 blocks (bi >= bj, 2080 blocks). Off-diag blocks emit both
// P[i][j] (normal) and P[j][i] (mirror, ushort4-coalesced) + den atomics both sides.
__global__ void __launch_bounds__(256) gemm_sim(
    const u16* __restrict__ U, const u64* __restrict__ maskw,
    u16* __restrict__ Pb, float* __restrict__ den)
{
  __shared__ __align__(16) u16 As[128 * 32];
  __shared__ __align__(16) u16 Bs[128 * 32];

  // decode linear block index -> lower-tri (bi, bj), bi >= bj
  const int b = blockIdx.x;
  int bi = (int)((sqrtf(8.0f * (float)b + 1.0f) - 1.0f) * 0.5f);
  while ((bi + 1) * (bi + 2) / 2 <= b) bi++;
  while (bi * (bi + 1) / 2 > b) bi--;
  const int bj = b - bi * (bi + 1) / 2;

  const int tid = threadIdx.x;
  const int w = tid >> 6;
  const int lane = tid & 63;
  const int lm = lane & 15;
  const int q = lane >> 4;
  const int row0 = bi * 128;
  const int col0 = bj * 128;
  const int RM = (w >> 1) * 64;
  const int RN = (w & 1) * 64;
  const int sr = tid >> 2;
  const int sk = (tid & 3) * 8;
  const bool diag = (bi == bj);

  f32x4 acc[4][4];
  #pragma unroll
  for (int a_ = 0; a_ < 4; a_++)
    #pragma unroll
    for (int b_ = 0; b_ < 4; b_++)
      acc[a_][b_] = (f32x4){0.f, 0.f, 0.f, 0.f};

  const size_t Abase = (size_t)row0 * DD;
  const size_t Bbase = (size_t)col0 * DD;

  for (int k0 = 0; k0 < DD; k0 += 32) {
    __syncthreads();
    gld_lds16(U + Abase + (size_t)sr * DD + k0 + sk,        (char*)As + w * 1024);
    gld_lds16(U + Abase + (size_t)(sr + 64) * DD + k0 + sk, (char*)As + 4096 + w * 1024);
    gld_lds16(U + Bbase + (size_t)sr * DD + k0 + sk,        (char*)Bs + w * 1024);
    gld_lds16(U + Bbase + (size_t)(sr + 64) * DD + k0 + sk, (char*)Bs + 4096 + w * 1024);
    __syncthreads();

    short8 af[4], bfr[4];
    #pragma unroll
    for (int mt = 0; mt < 4; mt++)
      af[mt] = *(const short8*)&As[(RM + mt * 16 + lm) * 32 + q * 8];
    #pragma unroll
    for (int nt = 0; nt < 4; nt++)
      bfr[nt] = *(const short8*)&Bs[(RN + nt * 16 + lm) * 32 + q * 8];

    #pragma unroll
    for (int mt = 0; mt < 4; mt++)
      #pragma unroll
      for (int nt = 0; nt < 4; nt++)
        acc[mt][nt] = __builtin_amdgcn_mfma_f32_16x16x32_bf16(af[mt], bfr[nt], acc[mt][nt], 0, 0, 0);
  }

  // C/D layout: col = lane&15 (lm), row = q*4 + reg (rr)
  const int wordIdx = (col0 + RN) >> 6;        // mask word for normal side
  const int word2Idx = (row0 + RM) >> 6;       // mask word for mirror side

  u64 wrd2[4];
  if (!diag) {
    #pragma unroll
    for (int nt = 0; nt < 4; nt++) {
      const int jc = col0 + RN + nt * 16 + lm;
      wrd2[nt] = maskw[(size_t)jc * (NN / 64) + word2Idx];
    }
  }

  float msum[4] = {0.f, 0.f, 0.f, 0.f};

  #pragma unroll
  for (int mt = 0; mt < 4; mt++) {
    const int ib = row0 + RM + mt * 16 + q * 4;
    float pm[4][4];  // [nt][rr] mirror values
    #pragma unroll
    for (int rr = 0; rr < 4; rr++) {
      const int i = ib + rr;
      const u64 wrd = maskw[(size_t)i * (NN / 64) + wordIdx];
      const int bit2 = mt * 16 + q * 4 + rr;   // == i - (row0 + RM)
      float psum = 0.f;
      #pragma unroll
      for (int nt = 0; nt < 4; nt++) {
        const int jc = col0 + RN + nt * 16 + lm;
        const float ev = __expf(acc[mt][nt][rr]);
        const bool on = ((wrd >> (nt * 16 + lm)) & 1ull) || (diag && i == jc);
        const float p = on ? ev : 0.0f;
        psum += p;
        Pb[(size_t)i * NN + jc] = f2bf(p);
        if (!diag) {
          const bool on2 = (wrd2[nt] >> bit2) & 1ull;
          const float pmv = on2 ? ev : 0.0f;
          pm[nt][rr] = pmv;
          msum[nt] += pmv;
        }
      }
      #pragma unroll
      for (int off = 8; off; off >>= 1) psum += __shfl_down(psum, off, 16);
      if (lm == 0) atomicAdd(&den[i], psum);
    }
    if (!diag) {
      #pragma unroll
      for (int nt = 0; nt < 4; nt++) {
        const int jc = col0 + RN + nt * 16 + lm;
        ushort4 m4;
        m4.x = f2bf(pm[nt][0]); m4.y = f2bf(pm[nt][1]);
        m4.z = f2bf(pm[nt][2]); m4.w = f2bf(pm[nt][3]);
        *(ushort4*)&Pb[(size_t)jc * NN + ib] = m4;
      }
    }
  }

  if (!diag) {
    #pragma unroll
    for (int nt = 0; nt < 4; nt++) {
      float s = msum[nt];
      s += __shfl_xor(s, 16);
      s += __shfl_xor(s, 32);
      if (q == 0) atomicAdd(&den[col0 + RN + nt * 16 + lm], s);
    }
  }
}

// out-GEMM: tile 128 rows x FULL N=512, 512 threads (8 waves, each 64x128).
// Split-K=8 via blockIdx.y; partial z stored bf16 at part + z*NN*DD.
__global__ void __launch_bounds__(512, 2) gemm_out(
    const u16* __restrict__ A,    // P [NN x NN]
    const u16* __restrict__ B,    // WhT [DD x NN]
    u16* __restrict__ part)
{
  __shared__ __align__(16) u16 As[128 * 32];   // 8 KB
  __shared__ __align__(16) u16 Bs[512 * 32];   // 32 KB

  const int tid = threadIdx.x;
  const int w = tid >> 6;        // 0..7
  const int lane = tid & 63;
  const int lm = lane & 15;
  const int q = lane >> 4;
  const int row0 = blockIdx.x * 128;
  const int z = blockIdx.y;      // 0..7
  const int RM = (w >> 2) * 64;  // 0/64
  const int RN = (w & 3) * 128;  // 0..384
  const int sr = tid >> 2;       // 0..127
  const int sk = (tid & 3) * 8;

  f32x4 acc[4][8];
  #pragma unroll
  for (int a_ = 0; a_ < 4; a_++)
    #pragma unroll
    for (int b_ = 0; b_ < 8; b_++)
      acc[a_][b_] = (f32x4){0.f, 0.f, 0.f, 0.f};

  const size_t Abase = (size_t)row0 * NN;
  const int kBegin = z * (NN / 8), kEnd = (z + 1) * (NN / 8);

  for (int k0 = kBegin; k0 < kEnd; k0 += 32) {
    __syncthreads();
    gld_lds16(A + Abase + (size_t)sr * NN + k0 + sk, (char*)As + w * 1024);
    #pragma unroll
    for (int c = 0; c < 4; c++)
      gld_lds16(B + (size_t)(c * 128 + sr) * NN + k0 + sk, (char*)Bs + c * 8192 + w * 1024);
    __syncthreads();

    short8 af[4], bfr[8];
    #pragma unroll
    for (int mt = 0; mt < 4; mt++)
      af[mt] = *(const short8*)&As[(RM + mt * 16 + lm) * 32 + q * 8];
    #pragma unroll
    for (int nt = 0; nt < 8; nt++)
      bfr[nt] = *(const short8*)&Bs[(RN + nt * 16 + lm) * 32 + q * 8];

    #pragma unroll
    for (int mt = 0; mt < 4; mt++)
      #pragma unroll
      for (int nt = 0; nt < 8; nt++)
        acc[mt][nt] = __builtin_amdgcn_mfma_f32_16x16x32_bf16(af[mt], bfr[nt], acc[mt][nt], 0, 0, 0);
  }

  u16* const pz = part + (size_t)z * NN * DD;
  #pragma unroll
  for (int mt = 0; mt < 4; mt++) {
    const int ib = row0 + RM + mt * 16 + q * 4;
    #pragma unroll
    for (int rr = 0; rr < 4; rr++) {
      const int i = ib + rr;
      #pragma unroll
      for (int nt = 0; nt < 8; nt++) {
        const int dc = RN + nt * 16 + lm;
        pz[(size_t)i * DD + dc] = f2bf(acc[mt][nt][rr]);
      }
    }
  }
}

// out = (sum of 8 bf16 partials) / den[row]; each thread handles 8 cols
__global__ void reduce8_kernel(const u16* __restrict__ part,
                               const float* __restrict__ den, float4* __restrict__ out) {
  const int idx = blockIdx.x * 256 + threadIdx.x;   // NN*DD/8 units of 8 cols
  const int row = idx >> 6;                          // 64 units per row
  const float dinv = 1.0f / den[row];
  float s[8] = {0, 0, 0, 0, 0, 0, 0, 0};
  #pragma unroll
  for (int zp = 0; zp < 8; zp++) {
    const uint4 u = ((const uint4*)(part + (size_t)zp * NN * DD))[idx];
    s[0] += __uint_as_float(u.x << 16); s[1] += __uint_as_float(u.x & 0xffff0000u);
    s[2] += __uint_as_float(u.y << 16); s[3] += __uint_as_float(u.y & 0xffff0000u);
    s[4] += __uint_as_float(u.z << 16); s[5] += __uint_as_float(u.z & 0xffff0000u);
    s[6] += __uint_as_float(u.w << 16); s[7] += __uint_as_float(u.w & 0xffff0000u);
  }
  float4 o0 = {s[0] * dinv, s[1] * dinv, s[2] * dinv, s[3] * dinv};
  float4 o1 = {s[4] * dinv, s[5] * dinv, s[6] * dinv, s[7] * dinv};
  out[idx * 2] = o0;
  out[idx * 2 + 1] = o1;
}

extern "C" void kernel_launch(void* const* d_in, const int* in_sizes, int n_in,
                              void* d_out, int out_size, void* d_ws, size_t ws_size,
                              hipStream_t stream) {
  const float* h = (const float*)d_in[0];
  const int* adj = (const int*)d_in[1];
  const float* W = (const float*)d_in[2];
  float* out = (float*)d_out;

  const size_t SZ_P    = (size_t)NN * NN * 2;          // 134.2 MB
  const size_t SZ_MASK = (size_t)NN * NN / 8;          // 8.4 MB
  const size_t SZ_WHT  = (size_t)DD * NN * 2;          // 8.4 MB
  const size_t SZ_HB   = (size_t)NN * DD * 2;          // 8.4 MB
  const size_t SZ_WB   = (size_t)DD * DD * 2;          // 0.5 MB
  const size_t SZ_U    = (size_t)NN * DD * 2;          // 8.4 MB
  const size_t SZ_WH   = (size_t)NN * DD * 4;          // 16.8 MB
  const size_t SZ_PART = (size_t)8 * NN * DD * 2;      // 67.1 MB
  const size_t NEEDED  = SZ_P + SZ_MASK + SZ_WHT + SZ_HB + SZ_WB + SZ_U + SZ_WH
                       + SZ_PART + 2 * (size_t)NN * 4;

  if (ws_size < NEEDED) {
    fill_kernel<<<256, 256, 0, stream>>>(out, out_size, 12345.0f);
    return;
  }

  char* ws = (char*)d_ws;
  size_t off = 0;
  u16*   P    = (u16*)(ws + off); off += SZ_P;
  u16*   mask = (u16*)(ws + off); off += SZ_MASK;
  u16*   WhT  = (u16*)(ws + off); off += SZ_WHT;
  u16*   hb   = (u16*)(ws + off); off += SZ_HB;
  u16*   Wb   = (u16*)(ws + off); off += SZ_WB;
  u16*   U    = (u16*)(ws + off); off += SZ_U;
  float* Wh   = (float*)(ws + off); off += SZ_WH;
  u16*   part = (u16*)(ws + off); off += SZ_PART;
  float* invn = (float*)(ws + off);
  float* den  = invn + NN;

  pack_adj_kernel<<<NN, 256, 0, stream>>>(adj, mask, den);
  cvt4_kernel<<<1024, 256, 0, stream>>>((const float4*)h, (ushort4*)hb, NN * DD / 4);
  cvt4_kernel<<<256, 256, 0, stream>>>((const float4*)W, (ushort4*)Wb, DD * DD / 4);
  // Wh = h @ W^T
  gemm_wh<<<dim3(DD / 128, NN / 128), 256, 0, stream>>>(hb, Wb, DD, DD, Wh);
  rownorm_kernel<<<NN, 64, 0, stream>>>(Wh, invn);
  u_wht_kernel<<<dim3(NN / 64, DD / 64), 256, 0, stream>>>(Wh, invn, U, WhT);
  // P = mask ? exp(U U^T) : 0 (bf16), symmetric lower-tri 128x128 + mirror, fused den
  gemm_sim<<<64 * 65 / 2, 256, 0, stream>>>(U, (const u64*)mask, P, den);
  // out partials: full-N tile, split-K=8 (P read exactly once)
  gemm_out<<<dim3(NN / 128, 8), 512, 0, stream>>>(P, WhT, part);
  // out = sum(partials) / den
  reduce8_kernel<<<NN * DD / 8 / 256, 256, 0, stream>>>(part, den, (float4*)out);
}